// Round 10
// baseline (208.027 us; speedup 1.0000x reference)
//
#include <hip/hip_runtime.h>
#include <hip/hip_bf16.h>
#include <stdint.h>

#define B_  2
#define T_  2048
#define D_  1024
#define H_  16
#define KS  64
#define M_  (B_*T_)    // 4096

typedef unsigned short u16;
typedef __bf16 bf16x8 __attribute__((ext_vector_type(8)));
typedef __bf16 bf16x4 __attribute__((ext_vector_type(4)));
typedef float  f32x4  __attribute__((ext_vector_type(4)));

#define AS1 __attribute__((address_space(1)))
#define AS3 __attribute__((address_space(3)))

__device__ inline u16 f2bf(float x){
  union { float f; uint32_t u; } v; v.f = x;
  uint32_t r = (v.u + 0x7fffu + ((v.u >> 16) & 1u)) >> 16;
  return (u16)r;
}

__device__ inline void gl_lds16(const u16* g, u16* l){
  __builtin_amdgcn_global_load_lds((AS1 void*)(const_cast<u16*>(g)),
                                   (AS3 void*)l, 16, 0, 0);
}

// ---------------- fused prep: x fp32->bf16  +  W transpose-convert ----------------
__global__ __launch_bounds__(256) void k_prep(const float* __restrict__ x,
                                              u16* __restrict__ xb,
                                              const float* __restrict__ W0,
                                              const float* __restrict__ W1,
                                              const float* __restrict__ W2,
                                              const float* __restrict__ W3,
                                              u16* __restrict__ wt){
  int bid = blockIdx.x, tid = threadIdx.x;
  if(bid < 4096){
    int i = bid * 256 + tid;
    float4 v = ((const float4*)x)[i];
    ushort4 o;
    o.x = f2bf(v.x); o.y = f2bf(v.y); o.z = f2bf(v.z); o.w = f2bf(v.w);
    ((ushort4*)xb)[i] = o;
  } else {
    int pid = bid - 4096;
    int z = pid >> 10, rem = pid & 1023;
    int by = rem >> 5, bx = rem & 31;
    const float* W = (z==0)?W0:(z==1)?W1:(z==2)?W2:W3;
    u16* o = wt + (size_t)z * 1024 * 1024;
    __shared__ float tile[32][33];
    int tx = tid & 31, ty = tid >> 5;               // 32 x 8
    int kb = by * 32, nb = bx * 32;
    for(int i=0;i<4;i++) tile[ty+8*i][tx] = W[(size_t)(kb+ty+8*i)*1024 + nb+tx];
    __syncthreads();
    for(int i=0;i<4;i++){
      int n = nb + ty + 8*i;
      o[(size_t)n*1024 + kb + tx] = f2bf(tile[tx][ty+8*i]);
    }
  }
}

// ---------------- QKV GEMM core (branch-free inner loop, template-unswitched) ----------------
template<bool CT>
__device__ inline void qkv_core(const u16* __restrict__ xb, const u16* __restrict__ BT,
                                int m0, int n0, u16* Asm, u16* Bsm,
                                f32x4 (&acc)[4][4],
                                int lane, int wm, int wn){
  int l15 = lane & 15, l4 = lane >> 4;
  int tid = threadIdx.x;
  int srow = tid >> 3, schunk = tid & 7;
  for(int kt=0; kt<16; ++kt){
    __syncthreads();
    int kb = kt * 64;
    for(int i=0;i<4;i++){
      int row = i*32 + srow;
      int gch = schunk ^ (row & 7);           // pre-swizzled global source (T2)
      gl_lds16(xb + (size_t)(m0+row)*1024 + kb + gch*8, Asm + row*64 + schunk*8);
      gl_lds16(BT + (size_t)(n0+row)*1024 + kb + gch*8, Bsm + row*64 + schunk*8);
    }
    __syncthreads();
    for(int c=0;c<2;c++){
      bf16x8 af[4], bfr[4];
      for(int mt=0;mt<4;mt++){
        int row = wm*64 + mt*16 + l15;
        int idx = (row*64 + c*32 + l4*8) ^ ((row & 7) << 3);
        af[mt] = *(const bf16x8*)(Asm + idx);
      }
      for(int nt=0;nt<4;nt++){
        int row = wn*64 + nt*16 + l15;
        int idx = (row*64 + c*32 + l4*8) ^ ((row & 7) << 3);
        bfr[nt] = *(const bf16x8*)(Bsm + idx);
      }
      for(int mt=0;mt<4;mt++)
        for(int nt=0;nt<4;nt++){
          if(CT)
            acc[mt][nt] = __builtin_amdgcn_mfma_f32_16x16x32_bf16(bfr[nt], af[mt], acc[mt][nt], 0,0,0);
          else
            acc[mt][nt] = __builtin_amdgcn_mfma_f32_16x16x32_bf16(af[mt], bfr[nt], acc[mt][nt], 0,0,0);
        }
    }
  }
}

// Q,K as C^T -> packed bf16x4 stores to [B,H,T,64]; V normal -> VT [B*H,64,T].
// Q pre-scaled by (1/8)*log2(e). XCD swizzle: each XCD owns an m-stripe.
__global__ __launch_bounds__(256) void k_gemm_qkv(const u16* __restrict__ xb,
                                                  const u16* __restrict__ wt,
                                                  const float* __restrict__ bq,
                                                  const float* __restrict__ bk,
                                                  const float* __restrict__ bv,
                                                  u16* __restrict__ qkv,
                                                  u16* __restrict__ vt){
  int bid = blockIdx.x;
  int sw  = (bid & 7) * 96 + (bid >> 3);      // 768 = 8 XCD x 96, bijective
  int mt_ = sw / 24, r = sw % 24;
  int widx = r >> 3;                          // 0..2 : q,k,v
  int n0   = (r & 7) * 128;
  int m0   = mt_ * 128;
  const u16* BT = wt + (size_t)widx * (1024*1024);
  const float* bias = (widx==0)?bq:(widx==1)?bk:bv;
  u16* out = qkv + (size_t)widx * (4*1024*1024);
  float oscale = (widx==0) ? 0.125f * 1.44269504088896f : 1.0f;

  __shared__ u16 Asm[128*64];
  __shared__ u16 Bsm[128*64];
  int t = threadIdx.x;
  int lane = t & 63, w = t >> 6, wm = w >> 1, wn = w & 1;
  int l15 = lane & 15, l4 = lane >> 4;
  f32x4 zero = {0.f,0.f,0.f,0.f};
  f32x4 acc[4][4];
  for(int i=0;i<4;i++) for(int j=0;j<4;j++) acc[i][j] = zero;

  if(widx < 2){
    qkv_core<true >(xb, BT, m0, n0, Asm, Bsm, acc, lane, wm, wn);
    for(int nt=0;nt<4;nt++){
      int nb = n0 + wn*64 + nt*16 + l4*4;
      float4 b4 = *(const float4*)&bias[nb];
      int h = nb >> 6, kk = nb & 63;
      for(int mt=0;mt<4;mt++){
        int m = m0 + wm*64 + mt*16 + l15;
        int b = m >> 11, tt = m & 2047;
        bf16x4 pk;
        pk[0] = (__bf16)((acc[mt][nt][0] + b4.x) * oscale);
        pk[1] = (__bf16)((acc[mt][nt][1] + b4.y) * oscale);
        pk[2] = (__bf16)((acc[mt][nt][2] + b4.z) * oscale);
        pk[3] = (__bf16)((acc[mt][nt][3] + b4.w) * oscale);
        *(bf16x4*)(out + (((size_t)(b*H_ + h)*T_ + tt) << 6) + kk) = pk;
      }
    }
  } else {
    qkv_core<false>(xb, BT, m0, n0, Asm, Bsm, acc, lane, wm, wn);
    for(int nt=0;nt<4;nt++){
      int nbase = n0 + wn*64 + nt*16 + l15;
      float bv_ = bias[nbase];
      int h = nbase >> 6, kk = nbase & 63;
      for(int mt=0;mt<4;mt++){
        int m = m0 + wm*64 + mt*16 + l4*4;    // 4 consecutive t
        int b = m >> 11, tt = m & 2047;
        bf16x4 pk;
        for(int r2=0;r2<4;r2++) pk[r2] = (__bf16)(acc[mt][nt][r2] + bv_);
        *(bf16x4*)(vt + (((size_t)(b*H_ + h)*64 + kk)*T_) + tt) = pk;
      }
    }
  }
}

// ---------------- flash attention: 32 q/wave, 2-wave blocks (4 barrier domains/CU) ----------------
// r9 was sync-bound (2 blocks/CU, nothing saturated). Same total waves, finer
// barrier granularity: 1024 blocks x 2 waves x 32q, LDS 40KB -> 4 blocks/CU.
__global__ __launch_bounds__(128, 2) void k_attn(const u16* __restrict__ Q,
                                                 const u16* __restrict__ Kg,
                                                 const u16* __restrict__ VT,
                                                 u16* __restrict__ attn_out){
  // XCD swizzle (1024 = 8 x 128): each XCD owns 4 (b,h) groups -> K/V L2-local
  int bx0 = blockIdx.x;
  int bx  = (bx0 & 7) * 128 + (bx0 >> 3);
  int qt = bx & 31, h = (bx >> 5) & 15, b = bx >> 9;
  int bh = b*H_ + h;
  const u16* Qh = Q  + (size_t)bh * T_ * 64;
  const u16* Kh = Kg + (size_t)bh * T_ * 64;
  const u16* Vh = VT + (size_t)bh * 64 * T_;
  __shared__ u16 Ksm[2][64*64];        // 16 KB
  __shared__ u16 Vsm[2][64*64];        // 16 KB
  __shared__ u16 Psm[2][32*64];        // 8 KB (per-wave 32 q x 64 k)
  int t = threadIdx.x, lane = t & 63, w = t >> 6;   // w in {0,1}
  int l15 = lane & 15, l4 = lane >> 4;

  // Q fragments: 2 sets x 2 chunks (cols q = l15 / l15+16)
  bf16x8 qf[2][2];
  for(int ss=0; ss<2; ++ss){
    int qrow = qt*64 + w*32 + ss*16 + l15;
    for(int c=0;c<2;c++)
      qf[ss][c] = *(const bf16x8*)(Qh + (size_t)qrow*64 + c*32 + l4*8);
  }

  bf16x8 ones;
  for(int j=0;j<8;j++) ones[j] = (__bf16)1.0f;

  f32x4 zero = {0.f,0.f,0.f,0.f};
  f32x4 accT[2][4];
  for(int ss=0;ss<2;ss++) for(int g=0;g<4;g++) accT[ss][g] = zero;
  f32x4 accL[2] = {zero, zero};
  float m_r[2] = {-3.0e38f, -3.0e38f};

  int srow = t >> 3, schunk = t & 7;   // srow 0..15 (128 threads)
  int gchS = schunk ^ (srow & 7);      // row&7 invariant under +16

  // prologue: stage tile 0 (4 row-passes each for K and V)
  for(int i=0;i<4;i++){
    int row = i*16 + srow;
    gl_lds16(Kh + (size_t)row*64 + gchS*8, &Ksm[0][row*64 + schunk*8]);
    gl_lds16(Vh + (size_t)row*T_ + gchS*8, &Vsm[0][row*64 + schunk*8]);
  }
  __syncthreads();

  auto body = [&](int tile, int cur){
    if(tile+1 < 32){
      int kvb = (tile+1)*64;
      for(int i=0;i<4;i++){
        int row = i*16 + srow;
        gl_lds16(Kh + (size_t)(kvb+row)*64 + gchS*8, &Ksm[cur^1][row*64 + schunk*8]);
        gl_lds16(Vh + (size_t)row*T_ + kvb + gchS*8, &Vsm[cur^1][row*64 + schunk*8]);
      }
    }

    // S^T = K · Q^T for both q-sets; K frags read ONCE, used twice
    f32x4 s_[2][4];
    for(int ss=0;ss<2;ss++) for(int g=0;g<4;g++) s_[ss][g] = zero;
    __builtin_amdgcn_s_setprio(1);
    for(int c=0;c<2;c++){
      for(int g=0;g<4;g++){
        int row = g*16 + l15;
        int idx = (row*64 + c*32 + l4*8) ^ ((row & 7) << 3);
        bf16x8 kf = *(const bf16x8*)(&Ksm[cur][idx]);
        s_[0][g] = __builtin_amdgcn_mfma_f32_16x16x32_bf16(kf, qf[0][c], s_[0][g], 0,0,0);
        s_[1][g] = __builtin_amdgcn_mfma_f32_16x16x32_bf16(kf, qf[1][c], s_[1][g], 0,0,0);
      }
    }
    __builtin_amdgcn_s_setprio(0);

    // per-lane softmax over 16 k values per set (+2 shuffles each)
    float pmax[2];
    #pragma unroll
    for(int ss=0;ss<2;ss++){
      float t0 = fmaxf(fmaxf(fmaxf(s_[ss][0][0], s_[ss][0][1]), s_[ss][0][2]), s_[ss][0][3]);
      float t1 = fmaxf(fmaxf(fmaxf(s_[ss][1][0], s_[ss][1][1]), s_[ss][1][2]), s_[ss][1][3]);
      float t2 = fmaxf(fmaxf(fmaxf(s_[ss][2][0], s_[ss][2][1]), s_[ss][2][2]), s_[ss][2][3]);
      float t3 = fmaxf(fmaxf(fmaxf(s_[ss][3][0], s_[ss][3][1]), s_[ss][3][2]), s_[ss][3][3]);
      float p = fmaxf(fmaxf(fmaxf(t0, t1), t2), t3);
      p = fmaxf(p, __shfl_xor(p, 16));
      p = fmaxf(p, __shfl_xor(p, 32));
      pmax[ss] = p;
    }
    // merged defer-rescale gate (T13)
    if(__any(fmaxf(pmax[0] - m_r[0], pmax[1] - m_r[1]) > 8.f)){
      #pragma unroll
      for(int ss=0;ss<2;ss++){
        float mnew  = fmaxf(m_r[ss], pmax[ss]);
        float alpha = __builtin_amdgcn_exp2f(m_r[ss] - mnew);
        m_r[ss] = mnew;
        for(int g=0;g<4;g++){
          f32x4 a = accT[ss][g];
          for(int r=0;r<4;r++) a[r] *= alpha;
          accT[ss][g] = a;
        }
        for(int r=0;r<4;r++) accL[ss][r] *= alpha;
      }
    }
    #pragma unroll
    for(int ss=0;ss<2;ss++)
      for(int g=0;g<4;g++)
        for(int r=0;r<4;r++)
          s_[ss][g][r] = __builtin_amdgcn_exp2f(s_[ss][g][r] - m_r[ss]);

    // pack P -> per-wave LDS [q=32][k=64], swizzled (row&7 invariant to +16)
    #pragma unroll
    for(int ss=0;ss<2;ss++){
      int row = ss*16 + l15;
      for(int g=0;g<4;g++){
        bf16x4 pk;
        for(int r=0;r<4;r++) pk[r] = (__bf16)s_[ss][g][r];
        int idx = (row*64 + g*16 + l4*4) ^ ((row & 7) << 3);
        *(bf16x4*)(&Psm[w][idx]) = pk;
      }
    }

    // O^T += V^T · P^T for both sets; V frags read ONCE, used twice
    __builtin_amdgcn_s_setprio(1);
    for(int c=0;c<2;c++){
      bf16x8 pf0, pf1;
      {
        int row0 = l15,      idx0 = (row0*64 + c*32 + l4*8) ^ ((row0 & 7) << 3);
        int row1 = 16 + l15, idx1 = (row1*64 + c*32 + l4*8) ^ ((row1 & 7) << 3);
        pf0 = *(const bf16x8*)(&Psm[w][idx0]);
        pf1 = *(const bf16x8*)(&Psm[w][idx1]);
      }
      accL[0] = __builtin_amdgcn_mfma_f32_16x16x32_bf16(ones, pf0, accL[0], 0,0,0);
      accL[1] = __builtin_amdgcn_mfma_f32_16x16x32_bf16(ones, pf1, accL[1], 0,0,0);
      for(int g=0;g<4;g++){
        int row = g*16 + l15;
        int idx = (row*64 + c*32 + l4*8) ^ ((row & 7) << 3);
        bf16x8 vf = *(const bf16x8*)(&Vsm[cur][idx]);
        accT[0][g] = __builtin_amdgcn_mfma_f32_16x16x32_bf16(vf, pf0, accT[0][g], 0,0,0);
        accT[1][g] = __builtin_amdgcn_mfma_f32_16x16x32_bf16(vf, pf1, accT[1][g], 0,0,0);
      }
    }
    __builtin_amdgcn_s_setprio(0);

    __syncthreads();
  };

  for(int t2=0; t2<16; ++t2){
    body(2*t2,   0);
    body(2*t2+1, 1);
  }

  // normalize + write O^T -> attn [B*T, H*64] bf16
  #pragma unroll
  for(int ss=0;ss<2;ss++){
    float oinv = 1.0f / accL[ss][0];
    int m = b*T_ + qt*64 + w*32 + ss*16 + l15;
    for(int g=0;g<4;g++){
      bf16x4 pk;
      for(int r=0;r<4;r++) pk[r] = (__bf16)(accT[ss][g][r] * oinv);
      *(bf16x4*)(attn_out + (size_t)m*1024 + h*64 + g*16 + l4*4) = pk;
    }
  }
}

// ---------------- final GEMM: attn[4096,1024] x WoT + bo -> fp32 out ----------------
// 64x128 tile, 1D grid 512 + XCD swizzle; C^T -> float4 stores
__global__ __launch_bounds__(256) void k_gemm_out(const u16* __restrict__ A,
                                                  const u16* __restrict__ BT,
                                                  const float* __restrict__ bias,
                                                  float* __restrict__ out){
  int bid = blockIdx.x;
  int sw  = (bid & 7) * 64 + (bid >> 3);     // 512 = 8 x 64
  int n0 = (sw & 7) * 128;
  int m0 = (sw >> 3) * 64;
  __shared__ u16 Asm[64*64];
  __shared__ u16 Bsm[128*64];
  int t = threadIdx.x;
  int lane = t & 63, w = t >> 6, wm = w >> 1, wn = w & 1;
  int l15 = lane & 15, l4 = lane >> 4;
  f32x4 zero = {0.f,0.f,0.f,0.f};
  f32x4 acc[2][4];
  for(int i=0;i<2;i++) for(int j=0;j<4;j++) acc[i][j] = zero;
  int srow = t >> 3, schunk = t & 7;

  for(int kt=0; kt<16; ++kt){
    __syncthreads();
    int kb = kt * 64;
    for(int i=0;i<2;i++){
      int row = i*32 + srow;
      int gch = schunk ^ (row & 7);
      gl_lds16(A  + (size_t)(m0+row)*1024 + kb + gch*8, Asm + row*64 + schunk*8);
    }
    for(int i=0;i<4;i++){
      int row = i*32 + srow;
      int gch = schunk ^ (row & 7);
      gl_lds16(BT + (size_t)(n0+row)*1024 + kb + gch*8, Bsm + row*64 + schunk*8);
    }
    __syncthreads();
    for(int c=0;c<2;c++){
      bf16x8 af[2], bfr[4];
      for(int mt=0;mt<2;mt++){
        int row = wm*32 + mt*16 + l15;
        int idx = (row*64 + c*32 + l4*8) ^ ((row & 7) << 3);
        af[mt] = *(const bf16x8*)(Asm + idx);
      }
      for(int nt=0;nt<4;nt++){
        int row = wn*64 + nt*16 + l15;
        int idx = (row*64 + c*32 + l4*8) ^ ((row & 7) << 3);
        bfr[nt] = *(const bf16x8*)(Bsm + idx);
      }
      for(int mt=0;mt<2;mt++)
        for(int nt=0;nt<4;nt++)
          acc[mt][nt] = __builtin_amdgcn_mfma_f32_16x16x32_bf16(bfr[nt], af[mt], acc[mt][nt], 0,0,0);
    }
  }
  for(int nt=0;nt<4;nt++){
    int nb = n0 + wn*64 + nt*16 + l4*4;
    float4 b4 = *(const float4*)&bias[nb];
    for(int mt=0;mt<2;mt++){
      int m = m0 + wm*32 + mt*16 + l15;
      float4 o;
      o.x = acc[mt][nt][0] + b4.x;
      o.y = acc[mt][nt][1] + b4.y;
      o.z = acc[mt][nt][2] + b4.z;
      o.w = acc[mt][nt][3] + b4.w;
      *(float4*)&out[(size_t)m*1024 + nb] = o;
    }
  }
}

extern "C" void kernel_launch(void* const* d_in, const int* in_sizes, int n_in,
                              void* d_out, int out_size, void* d_ws, size_t ws_size,
                              hipStream_t stream){
  const float* x  = (const float*)d_in[0];
  const float* Wq = (const float*)d_in[1];
  const float* bq = (const float*)d_in[2];
  const float* Wk = (const float*)d_in[3];
  const float* bk = (const float*)d_in[4];
  const float* Wv = (const float*)d_in[5];
  const float* bv = (const float*)d_in[6];
  const float* Wo = (const float*)d_in[7];
  const float* bo = (const float*)d_in[8];
  float* out = (float*)d_out;
  char* ws = (char*)d_ws;

  u16* xb  = (u16*)(ws);                    // 8 MB  : x bf16 [4096,1024]
  u16* wt  = (u16*)(ws + (8u  << 20));      // 8 MB  : WqT,WkT,WvT,WoT bf16
  u16* qkv = (u16*)(ws + (16u << 20));      // 16 MB : Q,K bf16 [BH,T,64]
  u16* vt  = (u16*)(ws + (40u << 20));      // 8 MB  : VT bf16 [BH,64,T]
  u16* at  = (u16*)(ws + (48u << 20));      // 8 MB  : attn bf16 [4096,1024]

  k_prep    <<<8192, 256, 0, stream>>>(x, xb, Wq, Wk, Wv, Wo, wt);
  k_gemm_qkv<<<768,  256, 0, stream>>>(xb, wt, bq, bk, bv, qkv, vt);
  k_attn    <<<1024, 128, 0, stream>>>(qkv, qkv + (size_t)4*1024*1024, vt, at);
  k_gemm_out<<<512,  256, 0, stream>>>(at, wt + (size_t)3*1024*1024, bo, out);
}

// Round 11
// 201.459 us; speedup vs baseline: 1.0326x; 1.0326x over previous
//
#include <hip/hip_runtime.h>
#include <hip/hip_bf16.h>
#include <stdint.h>

#define B_  2
#define T_  2048
#define D_  1024
#define H_  16
#define KS  64
#define M_  (B_*T_)    // 4096

typedef unsigned short u16;
typedef __bf16 bf16x8 __attribute__((ext_vector_type(8)));
typedef __bf16 bf16x4 __attribute__((ext_vector_type(4)));
typedef float  f32x4  __attribute__((ext_vector_type(4)));

#define AS1 __attribute__((address_space(1)))
#define AS3 __attribute__((address_space(3)))

__device__ inline u16 f2bf(float x){
  union { float f; uint32_t u; } v; v.f = x;
  uint32_t r = (v.u + 0x7fffu + ((v.u >> 16) & 1u)) >> 16;
  return (u16)r;
}

__device__ inline void gl_lds16(const u16* g, u16* l){
  __builtin_amdgcn_global_load_lds((AS1 void*)(const_cast<u16*>(g)),
                                   (AS3 void*)l, 16, 0, 0);
}

// ---------------- fused prep: x fp32->bf16  +  W transpose-convert (ushort4 stores) ----------------
__global__ __launch_bounds__(256) void k_prep(const float* __restrict__ x,
                                              u16* __restrict__ xb,
                                              const float* __restrict__ W0,
                                              const float* __restrict__ W1,
                                              const float* __restrict__ W2,
                                              const float* __restrict__ W3,
                                              u16* __restrict__ wt){
  int bid = blockIdx.x, tid = threadIdx.x;
  if(bid < 4096){
    int i = bid * 256 + tid;
    float4 v = ((const float4*)x)[i];
    ushort4 o;
    o.x = f2bf(v.x); o.y = f2bf(v.y); o.z = f2bf(v.z); o.w = f2bf(v.w);
    ((ushort4*)xb)[i] = o;
  } else {
    int pid = bid - 4096;
    int z = pid >> 10, rem = pid & 1023;
    int by = rem >> 5, bx = rem & 31;
    const float* W = (z==0)?W0:(z==1)?W1:(z==2)?W2:W3;
    u16* o = wt + (size_t)z * 1024 * 1024;
    __shared__ float tile[32][33];
    int tx = tid & 31, ty = tid >> 5;               // 32 x 8
    int kb = by * 32, nb = bx * 32;
    for(int i=0;i<4;i++) tile[ty+8*i][tx] = W[(size_t)(kb+ty+8*i)*1024 + nb+tx];
    __syncthreads();
    // write 4 consecutive k per thread -> ushort4 (8B) stores
    int n = tid >> 3, ch = tid & 7;
    ushort4 v;
    v.x = f2bf(tile[ch*4+0][n]);
    v.y = f2bf(tile[ch*4+1][n]);
    v.z = f2bf(tile[ch*4+2][n]);
    v.w = f2bf(tile[ch*4+3][n]);
    *(ushort4*)(o + (size_t)(nb+n)*1024 + kb + ch*4) = v;
  }
}

// ---------------- QKV GEMM core (branch-free inner loop, template-unswitched) ----------------
template<bool CT>
__device__ inline void qkv_core(const u16* __restrict__ xb, const u16* __restrict__ BT,
                                int m0, int n0, u16* Asm, u16* Bsm,
                                f32x4 (&acc)[4][4],
                                int lane, int wm, int wn){
  int l15 = lane & 15, l4 = lane >> 4;
  int tid = threadIdx.x;
  int srow = tid >> 3, schunk = tid & 7;
  for(int kt=0; kt<16; ++kt){
    __syncthreads();
    int kb = kt * 64;
    for(int i=0;i<4;i++){
      int row = i*32 + srow;
      int gch = schunk ^ (row & 7);           // pre-swizzled global source (T2)
      gl_lds16(xb + (size_t)(m0+row)*1024 + kb + gch*8, Asm + row*64 + schunk*8);
      gl_lds16(BT + (size_t)(n0+row)*1024 + kb + gch*8, Bsm + row*64 + schunk*8);
    }
    __syncthreads();
    for(int c=0;c<2;c++){
      bf16x8 af[4], bfr[4];
      for(int mt=0;mt<4;mt++){
        int row = wm*64 + mt*16 + l15;
        int idx = (row*64 + c*32 + l4*8) ^ ((row & 7) << 3);
        af[mt] = *(const bf16x8*)(Asm + idx);
      }
      for(int nt=0;nt<4;nt++){
        int row = wn*64 + nt*16 + l15;
        int idx = (row*64 + c*32 + l4*8) ^ ((row & 7) << 3);
        bfr[nt] = *(const bf16x8*)(Bsm + idx);
      }
      for(int mt=0;mt<4;mt++)
        for(int nt=0;nt<4;nt++){
          if(CT)
            acc[mt][nt] = __builtin_amdgcn_mfma_f32_16x16x32_bf16(bfr[nt], af[mt], acc[mt][nt], 0,0,0);
          else
            acc[mt][nt] = __builtin_amdgcn_mfma_f32_16x16x32_bf16(af[mt], bfr[nt], acc[mt][nt], 0,0,0);
        }
    }
  }
}

// Q,K as C^T -> packed bf16x4 stores to [B,H,T,64]; V normal -> VT [B*H,64,T].
// Q pre-scaled by (1/8)*log2(e). XCD swizzle: each XCD owns an m-stripe.
__global__ __launch_bounds__(256) void k_gemm_qkv(const u16* __restrict__ xb,
                                                  const u16* __restrict__ wt,
                                                  const float* __restrict__ bq,
                                                  const float* __restrict__ bk,
                                                  const float* __restrict__ bv,
                                                  u16* __restrict__ qkv,
                                                  u16* __restrict__ vt){
  int bid = blockIdx.x;
  int sw  = (bid & 7) * 96 + (bid >> 3);      // 768 = 8 XCD x 96, bijective
  int mt_ = sw / 24, r = sw % 24;
  int widx = r >> 3;                          // 0..2 : q,k,v
  int n0   = (r & 7) * 128;
  int m0   = mt_ * 128;
  const u16* BT = wt + (size_t)widx * (1024*1024);
  const float* bias = (widx==0)?bq:(widx==1)?bk:bv;
  u16* out = qkv + (size_t)widx * (4*1024*1024);
  float oscale = (widx==0) ? 0.125f * 1.44269504088896f : 1.0f;

  __shared__ u16 Asm[128*64];
  __shared__ u16 Bsm[128*64];
  int t = threadIdx.x;
  int lane = t & 63, w = t >> 6, wm = w >> 1, wn = w & 1;
  int l15 = lane & 15, l4 = lane >> 4;
  f32x4 zero = {0.f,0.f,0.f,0.f};
  f32x4 acc[4][4];
  for(int i=0;i<4;i++) for(int j=0;j<4;j++) acc[i][j] = zero;

  if(widx < 2){
    qkv_core<true >(xb, BT, m0, n0, Asm, Bsm, acc, lane, wm, wn);
    for(int nt=0;nt<4;nt++){
      int nb = n0 + wn*64 + nt*16 + l4*4;
      float4 b4 = *(const float4*)&bias[nb];
      int h = nb >> 6, kk = nb & 63;
      for(int mt=0;mt<4;mt++){
        int m = m0 + wm*64 + mt*16 + l15;
        int b = m >> 11, tt = m & 2047;
        bf16x4 pk;
        pk[0] = (__bf16)((acc[mt][nt][0] + b4.x) * oscale);
        pk[1] = (__bf16)((acc[mt][nt][1] + b4.y) * oscale);
        pk[2] = (__bf16)((acc[mt][nt][2] + b4.z) * oscale);
        pk[3] = (__bf16)((acc[mt][nt][3] + b4.w) * oscale);
        *(bf16x4*)(out + (((size_t)(b*H_ + h)*T_ + tt) << 6) + kk) = pk;
      }
    }
  } else {
    qkv_core<false>(xb, BT, m0, n0, Asm, Bsm, acc, lane, wm, wn);
    for(int nt=0;nt<4;nt++){
      int nbase = n0 + wn*64 + nt*16 + l15;
      float bv_ = bias[nbase];
      int h = nbase >> 6, kk = nbase & 63;
      for(int mt=0;mt<4;mt++){
        int m = m0 + wm*64 + mt*16 + l4*4;    // 4 consecutive t
        int b = m >> 11, tt = m & 2047;
        bf16x4 pk;
        for(int r2=0;r2<4;r2++) pk[r2] = (__bf16)(acc[mt][nt][r2] + bv_);
        *(bf16x4*)(vt + (((size_t)(b*H_ + h)*64 + kk)*T_) + tt) = pk;
      }
    }
  }
}

// ---------------- flash attention: r9 config (best known: 62.1 us) ----------------
// 4 waves x 32 q/wave (2 q-sets share K/V frags), block = 128 q, grid 512.
__global__ __launch_bounds__(256, 2) void k_attn(const u16* __restrict__ Q,
                                                 const u16* __restrict__ Kg,
                                                 const u16* __restrict__ VT,
                                                 u16* __restrict__ attn_out){
  // XCD swizzle (512 = 8 x 64): each XCD owns 4 (b,h) groups -> K/V L2-local
  int bx0 = blockIdx.x;
  int bx  = (bx0 & 7) * 64 + (bx0 >> 3);
  int qt = bx & 15, h = (bx >> 4) & 15, b = bx >> 8;
  int bh = b*H_ + h;
  const u16* Qh = Q  + (size_t)bh * T_ * 64;
  const u16* Kh = Kg + (size_t)bh * T_ * 64;
  const u16* Vh = VT + (size_t)bh * 64 * T_;
  __shared__ u16 Ksm[2][64*64];        // 16 KB
  __shared__ u16 Vsm[2][64*64];        // 16 KB
  __shared__ u16 Psm[4][32*64];        // 16 KB (per-wave 32 q x 64 k)
  int t = threadIdx.x, lane = t & 63, w = t >> 6;
  int l15 = lane & 15, l4 = lane >> 4;

  // Q fragments: 2 sets x 2 chunks (cols q = l15 / l15+16)
  bf16x8 qf[2][2];
  for(int ss=0; ss<2; ++ss){
    int qrow = qt*128 + w*32 + ss*16 + l15;
    for(int c=0;c<2;c++)
      qf[ss][c] = *(const bf16x8*)(Qh + (size_t)qrow*64 + c*32 + l4*8);
  }

  bf16x8 ones;
  for(int j=0;j<8;j++) ones[j] = (__bf16)1.0f;

  f32x4 zero = {0.f,0.f,0.f,0.f};
  f32x4 accT[2][4];
  for(int ss=0;ss<2;ss++) for(int g=0;g<4;g++) accT[ss][g] = zero;
  f32x4 accL[2] = {zero, zero};
  float m_r[2] = {-3.0e38f, -3.0e38f};

  int srow = t >> 3, schunk = t & 7;
  int gchS = schunk ^ (srow & 7);

  // prologue: stage tile 0
  gl_lds16(Kh + (size_t)srow*64      + gchS*8, &Ksm[0][srow*64      + schunk*8]);
  gl_lds16(Kh + (size_t)(srow+32)*64 + gchS*8, &Ksm[0][(srow+32)*64 + schunk*8]);
  gl_lds16(Vh + (size_t)srow*T_      + gchS*8, &Vsm[0][srow*64      + schunk*8]);
  gl_lds16(Vh + (size_t)(srow+32)*T_ + gchS*8, &Vsm[0][(srow+32)*64 + schunk*8]);
  __syncthreads();

  auto body = [&](int tile, int cur){
    if(tile+1 < 32){
      int kvb = (tile+1)*64;
      gl_lds16(Kh + (size_t)(kvb+srow)*64    + gchS*8, &Ksm[cur^1][srow*64      + schunk*8]);
      gl_lds16(Kh + (size_t)(kvb+srow+32)*64 + gchS*8, &Ksm[cur^1][(srow+32)*64 + schunk*8]);
      gl_lds16(Vh + (size_t)srow*T_      + kvb + gchS*8, &Vsm[cur^1][srow*64      + schunk*8]);
      gl_lds16(Vh + (size_t)(srow+32)*T_ + kvb + gchS*8, &Vsm[cur^1][(srow+32)*64 + schunk*8]);
    }

    // S^T = K · Q^T for both q-sets; K frags read ONCE, used twice
    f32x4 s_[2][4];
    for(int ss=0;ss<2;ss++) for(int g=0;g<4;g++) s_[ss][g] = zero;
    __builtin_amdgcn_s_setprio(1);
    for(int c=0;c<2;c++){
      for(int g=0;g<4;g++){
        int row = g*16 + l15;
        int idx = (row*64 + c*32 + l4*8) ^ ((row & 7) << 3);
        bf16x8 kf = *(const bf16x8*)(&Ksm[cur][idx]);
        s_[0][g] = __builtin_amdgcn_mfma_f32_16x16x32_bf16(kf, qf[0][c], s_[0][g], 0,0,0);
        s_[1][g] = __builtin_amdgcn_mfma_f32_16x16x32_bf16(kf, qf[1][c], s_[1][g], 0,0,0);
      }
    }
    __builtin_amdgcn_s_setprio(0);

    // per-lane softmax over 16 k values per set (+2 shuffles each)
    float pmax[2];
    #pragma unroll
    for(int ss=0;ss<2;ss++){
      float t0 = fmaxf(fmaxf(fmaxf(s_[ss][0][0], s_[ss][0][1]), s_[ss][0][2]), s_[ss][0][3]);
      float t1 = fmaxf(fmaxf(fmaxf(s_[ss][1][0], s_[ss][1][1]), s_[ss][1][2]), s_[ss][1][3]);
      float t2 = fmaxf(fmaxf(fmaxf(s_[ss][2][0], s_[ss][2][1]), s_[ss][2][2]), s_[ss][2][3]);
      float t3 = fmaxf(fmaxf(fmaxf(s_[ss][3][0], s_[ss][3][1]), s_[ss][3][2]), s_[ss][3][3]);
      float p = fmaxf(fmaxf(fmaxf(t0, t1), t2), t3);
      p = fmaxf(p, __shfl_xor(p, 16));
      p = fmaxf(p, __shfl_xor(p, 32));
      pmax[ss] = p;
    }
    // merged defer-rescale gate (T13)
    if(__any(fmaxf(pmax[0] - m_r[0], pmax[1] - m_r[1]) > 8.f)){
      #pragma unroll
      for(int ss=0;ss<2;ss++){
        float mnew  = fmaxf(m_r[ss], pmax[ss]);
        float alpha = __builtin_amdgcn_exp2f(m_r[ss] - mnew);
        m_r[ss] = mnew;
        for(int g=0;g<4;g++){
          f32x4 a = accT[ss][g];
          for(int r=0;r<4;r++) a[r] *= alpha;
          accT[ss][g] = a;
        }
        for(int r=0;r<4;r++) accL[ss][r] *= alpha;
      }
    }
    #pragma unroll
    for(int ss=0;ss<2;ss++)
      for(int g=0;g<4;g++)
        for(int r=0;r<4;r++)
          s_[ss][g][r] = __builtin_amdgcn_exp2f(s_[ss][g][r] - m_r[ss]);

    // pack P -> per-wave LDS [q=32][k=64], swizzled (row&7 invariant to +16)
    #pragma unroll
    for(int ss=0;ss<2;ss++){
      int row = ss*16 + l15;
      for(int g=0;g<4;g++){
        bf16x4 pk;
        for(int r=0;r<4;r++) pk[r] = (__bf16)s_[ss][g][r];
        int idx = (row*64 + g*16 + l4*4) ^ ((row & 7) << 3);
        *(bf16x4*)(&Psm[w][idx]) = pk;
      }
    }

    // O^T += V^T · P^T for both sets; V frags read ONCE, used twice
    __builtin_amdgcn_s_setprio(1);
    for(int c=0;c<2;c++){
      bf16x8 pf0, pf1;
      {
        int row0 = l15,      idx0 = (row0*64 + c*32 + l4*8) ^ ((row0 & 7) << 3);
        int row1 = 16 + l15, idx1 = (row1*64 + c*32 + l4*8) ^ ((row1 & 7) << 3);
        pf0 = *(const bf16x8*)(&Psm[w][idx0]);
        pf1 = *(const bf16x8*)(&Psm[w][idx1]);
      }
      accL[0] = __builtin_amdgcn_mfma_f32_16x16x32_bf16(ones, pf0, accL[0], 0,0,0);
      accL[1] = __builtin_amdgcn_mfma_f32_16x16x32_bf16(ones, pf1, accL[1], 0,0,0);
      for(int g=0;g<4;g++){
        int row = g*16 + l15;
        int idx = (row*64 + c*32 + l4*8) ^ ((row & 7) << 3);
        bf16x8 vf = *(const bf16x8*)(&Vsm[cur][idx]);
        accT[0][g] = __builtin_amdgcn_mfma_f32_16x16x32_bf16(vf, pf0, accT[0][g], 0,0,0);
        accT[1][g] = __builtin_amdgcn_mfma_f32_16x16x32_bf16(vf, pf1, accT[1][g], 0,0,0);
      }
    }
    __builtin_amdgcn_s_setprio(0);

    __syncthreads();
  };

  for(int t2=0; t2<16; ++t2){
    body(2*t2,   0);
    body(2*t2+1, 1);
  }

  // normalize + write O^T -> attn [B*T, H*64] bf16
  #pragma unroll
  for(int ss=0;ss<2;ss++){
    float oinv = 1.0f / accL[ss][0];
    int m = b*T_ + qt*128 + w*32 + ss*16 + l15;
    for(int g=0;g<4;g++){
      bf16x4 pk;
      for(int r=0;r<4;r++) pk[r] = (__bf16)(accT[ss][g][r] * oinv);
      *(bf16x4*)(attn_out + (size_t)m*1024 + h*64 + g*16 + l4*4) = pk;
    }
  }
}

// ---------------- final GEMM: attn[4096,1024] x WoT + bo -> fp32 out ----------------
// 64x64 tile, grid 1024 = 4 blocks/CU (barrier drains overlap); C^T -> float4 stores
__global__ __launch_bounds__(256) void k_gemm_out(const u16* __restrict__ A,
                                                  const u16* __restrict__ BT,
                                                  const float* __restrict__ bias,
                                                  float* __restrict__ out){
  int bid = blockIdx.x;
  int sw  = (bid & 7) * 128 + (bid >> 3);    // 1024 = 8 x 128, bijective
  int n0 = (sw & 15) * 64;
  int m0 = (sw >> 4) * 64;
  __shared__ u16 Asm[64*64];                 // 8 KB
  __shared__ u16 Bsm[64*64];                 // 8 KB
  int t = threadIdx.x;
  int lane = t & 63, w = t >> 6, wm = w >> 1, wn = w & 1;
  int l15 = lane & 15, l4 = lane >> 4;
  f32x4 zero = {0.f,0.f,0.f,0.f};
  f32x4 acc[2][2];
  for(int i=0;i<2;i++) for(int j=0;j<2;j++) acc[i][j] = zero;
  int srow = t >> 3, schunk = t & 7;

  for(int kt=0; kt<16; ++kt){
    __syncthreads();
    int kb = kt * 64;
    for(int i=0;i<2;i++){
      int row = i*32 + srow;
      int gch = schunk ^ (row & 7);
      gl_lds16(A  + (size_t)(m0+row)*1024 + kb + gch*8, Asm + row*64 + schunk*8);
      gl_lds16(BT + (size_t)(n0+row)*1024 + kb + gch*8, Bsm + row*64 + schunk*8);
    }
    __syncthreads();
    for(int c=0;c<2;c++){
      bf16x8 af[2], bfr[2];
      for(int mt=0;mt<2;mt++){
        int row = wm*32 + mt*16 + l15;
        int idx = (row*64 + c*32 + l4*8) ^ ((row & 7) << 3);
        af[mt] = *(const bf16x8*)(Asm + idx);
      }
      for(int nt=0;nt<2;nt++){
        int row = wn*32 + nt*16 + l15;
        int idx = (row*64 + c*32 + l4*8) ^ ((row & 7) << 3);
        bfr[nt] = *(const bf16x8*)(Bsm + idx);
      }
      for(int mt=0;mt<2;mt++)
        for(int nt=0;nt<2;nt++)
          acc[mt][nt] = __builtin_amdgcn_mfma_f32_16x16x32_bf16(bfr[nt], af[mt], acc[mt][nt], 0,0,0);
    }
  }
  // C^T epilogue: reg-axis = n -> float4 stores
  for(int nt=0;nt<2;nt++){
    int nb = n0 + wn*32 + nt*16 + l4*4;
    float4 b4 = *(const float4*)&bias[nb];
    for(int mt=0;mt<2;mt++){
      int m = m0 + wm*32 + mt*16 + l15;
      float4 o;
      o.x = acc[mt][nt][0] + b4.x;
      o.y = acc[mt][nt][1] + b4.y;
      o.z = acc[mt][nt][2] + b4.z;
      o.w = acc[mt][nt][3] + b4.w;
      *(float4*)&out[(size_t)m*1024 + nb] = o;
    }
  }
}

extern "C" void kernel_launch(void* const* d_in, const int* in_sizes, int n_in,
                              void* d_out, int out_size, void* d_ws, size_t ws_size,
                              hipStream_t stream){
  const float* x  = (const float*)d_in[0];
  const float* Wq = (const float*)d_in[1];
  const float* bq = (const float*)d_in[2];
  const float* Wk = (const float*)d_in[3];
  const float* bk = (const float*)d_in[4];
  const float* Wv = (const float*)d_in[5];
  const float* bv = (const float*)d_in[6];
  const float* Wo = (const float*)d_in[7];
  const float* bo = (const float*)d_in[8];
  float* out = (float*)d_out;
  char* ws = (char*)d_ws;

  u16* xb  = (u16*)(ws);                    // 8 MB  : x bf16 [4096,1024]
  u16* wt  = (u16*)(ws + (8u  << 20));      // 8 MB  : WqT,WkT,WvT,WoT bf16
  u16* qkv = (u16*)(ws + (16u << 20));      // 16 MB : Q,K bf16 [BH,T,64]
  u16* vt  = (u16*)(ws + (40u << 20));      // 8 MB  : VT bf16 [BH,64,T]
  u16* at  = (u16*)(ws + (48u << 20));      // 8 MB  : attn bf16 [4096,1024]

  k_prep    <<<8192, 256, 0, stream>>>(x, xb, Wq, Wk, Wv, Wo, wt);
  k_gemm_qkv<<<768,  256, 0, stream>>>(xb, wt, bq, bk, bv, qkv, vt);
  k_attn    <<<512,  256, 0, stream>>>(qkv, qkv + (size_t)4*1024*1024, vt, at);
  k_gemm_out<<<1024, 256, 0, stream>>>(at, wt + (size_t)3*1024*1024, bo, out);
}